// Round 8
// baseline (370.677 us; speedup 1.0000x reference)
//
#include <hip/hip_runtime.h>
#include <hip/hip_bf16.h>
#include <math.h>

#define DTC 0.01f

typedef __attribute__((ext_vector_type(8))) short short8;   // 8 x bf16 (4 VGPRs)
typedef __attribute__((ext_vector_type(4))) float f32x4;    // MFMA C/D
typedef unsigned short bf16raw;

__device__ __forceinline__ bf16raw f2bf(float f){
  union { unsigned u; float f; } v; v.f = f;
  unsigned r = v.u + 0x7FFF + ((v.u >> 16) & 1u);   // round-to-nearest-even
  return (bf16raw)(r >> 16);
}

// Load 8 consecutive fp32, round to 8 bf16.
__device__ __forceinline__ short8 ld8f(const float* __restrict__ p){
  float4 a = *(const float4*)p;
  float4 b = *(const float4*)(p + 4);
  short8 r;
  r[0] = (short)f2bf(a.x); r[1] = (short)f2bf(a.y);
  r[2] = (short)f2bf(a.z); r[3] = (short)f2bf(a.w);
  r[4] = (short)f2bf(b.x); r[5] = (short)f2bf(b.y);
  r[6] = (short)f2bf(b.z); r[7] = (short)f2bf(b.w);
  return r;
}

// ---------------------------------------------------------------------------
// Async-stage ITERS*16 rows x 32 bf16 -> LDS [row][32], T2-swizzled.
// LDS dest linear (global_load_lds HW requirement); 16B k-slot permuted on
// the GLOBAL side (rule #21): slot (lane&3) holds k-chunk (lane&3)^((lane>>3)&3).
// Reader applies the same involution -> 2-way (free) bank access.
// ---------------------------------------------------------------------------
template<int ITERS>
__device__ __forceinline__ void stage_async(const bf16raw* __restrict__ src, long ld,
                                            long row0, int k0, bf16raw* lds,
                                            int wave, int lane){
  int kchunk = (lane & 3) ^ ((lane >> 3) & 3);
#pragma unroll
  for (int i = 0; i < ITERS; ++i){
    int r0 = (wave*ITERS + i) * 16;
    long row = row0 + r0 + (lane >> 2);
    const bf16raw* gp = src + row*ld + k0 + kchunk*8;
    bf16raw* lp = lds + r0*32;
    __builtin_amdgcn_global_load_lds((const __attribute__((address_space(1))) void*)gp,
                                     (__attribute__((address_space(3))) void*)lp,
                                     16, 0, 0);
  }
}

// One BK=32 step: MI A-frags + NI B-frags (ds_read_b128, swizzled slot) + MI*NI MFMA.
template<int MI, int NI>
__device__ __forceinline__ void mma_tile(const bf16raw* Alds, const bf16raw* Blds,
                                         f32x4 acc[MI][NI], int wm, int wn, int quad, int t16){
  short8 af[MI], bfr[NI];
  int sw = (quad ^ ((t16 >> 1) & 3)) * 8;   // physical 16B slot for this lane's rows
#pragma unroll
  for (int mi = 0; mi < MI; ++mi)
    af[mi] = *(const short8*)(Alds + (wm*(MI*16) + mi*16 + t16)*32 + sw);
#pragma unroll
  for (int ni = 0; ni < NI; ++ni)
    bfr[ni] = *(const short8*)(Blds + (wn*(NI*16) + ni*16 + t16)*32 + sw);
#pragma unroll
  for (int mi = 0; mi < MI; ++mi)
#pragma unroll
    for (int ni = 0; ni < NI; ++ni)
      acc[mi][ni] = __builtin_amdgcn_mfma_f32_16x16x32_bf16(af[mi], bfr[ni], acc[mi][ni], 0, 0, 0);
}

// ---------------------------------------------------------------------------
// Prep: fp32 -> bf16 for u, [W_omega|W_zeta|W_B] (concat), C, D_mat.
// Grid-stride, 2048 blocks.
// ---------------------------------------------------------------------------
extern "C" __global__ void k_prep(const float* __restrict__ u,
    const float* __restrict__ Wom, const float* __restrict__ Wze,
    const float* __restrict__ WB, const float* __restrict__ Cm,
    const float* __restrict__ Dm, bf16raw* __restrict__ u_bf,
    bf16raw* __restrict__ Wcat, bf16raw* __restrict__ C_bf,
    bf16raw* __restrict__ Dm_bf){
  for (long g = (long)blockIdx.x * 256 + threadIdx.x; g < 2277376;
       g += (long)gridDim.x * 256){
    const float* src; bf16raw* dst; long o;
    if      (g < 2097152){ src = u;   dst = u_bf;          o = g; }
    else if (g < 2105344){ src = Wom; dst = Wcat;          o = g - 2097152; }
    else if (g < 2113536){ src = Wze; dst = Wcat + 65536;  o = g - 2105344; }
    else if (g < 2129920){ src = WB;  dst = Wcat + 131072; o = g - 2113536; }
    else if (g < 2146304){ src = Cm;  dst = C_bf;          o = g - 2129920; }
    else                 { src = Dm;  dst = Dm_bf;         o = g - 2146304; }
    *(short8*)(dst + o*8) = ld8f(src + o*8);
  }
}

// ---------------------------------------------------------------------------
// K1: P[bt][n] = sum_d u[bt][d] * Wcat[n][d]  (16384 x 256, K=1024), fp32 out.
// Tile 64x64, 1024 blocks (4/CU). 3-buffer single-barrier pipeline.
// ---------------------------------------------------------------------------
extern "C" __global__ __launch_bounds__(256, 4) void k_gemm_p(
    const bf16raw* __restrict__ u_bf, const bf16raw* __restrict__ Wcat,
    float* __restrict__ P){
  __shared__ __align__(16) bf16raw Alds[3*64*32];    // 12 KB
  __shared__ __align__(16) bf16raw Blds[3*64*32];    // 12 KB
  int tid = threadIdx.x, wave = tid >> 6, lane = tid & 63;
  int quad = lane >> 4, t16 = lane & 15;
  int wm = wave >> 1, wn = wave & 1;                 // wave tile 32x32
  int id  = blockIdx.y * gridDim.x + blockIdx.x;
  int sid = (id & 7) * 128 + (id >> 3);
  long row0 = (long)(sid >> 2) * 64;
  int  col0 = (sid & 3) * 64;
  f32x4 acc[2][2] = {};

  auto stage = [&](int kt, int buf){
    stage_async<1>(u_bf, 1024, row0, kt*32, Alds + buf*(64*32), wave, lane);
    stage_async<1>(Wcat, 1024, col0, kt*32, Blds + buf*(64*32), wave, lane);
  };

  stage(0, 0);
  stage(1, 1);
  int rd = 0;                                        // rd = s % 3
  for (int s = 0; s < 30; ++s){
    asm volatile("s_waitcnt vmcnt(2)" ::: "memory");
    __builtin_amdgcn_s_barrier();
    __builtin_amdgcn_sched_barrier(0);
    int st = rd >= 1 ? rd - 1 : 2;                   // (s+2)%3
    stage(s + 2, st);
    __builtin_amdgcn_s_setprio(1);
    mma_tile<2,2>(Alds + rd*(64*32), Blds + rd*(64*32), acc, wm, wn, quad, t16);
    __builtin_amdgcn_s_setprio(0);
    rd = rd < 2 ? rd + 1 : 0;
  }
  asm volatile("s_waitcnt vmcnt(2)" ::: "memory");
  __builtin_amdgcn_s_barrier();
  __builtin_amdgcn_sched_barrier(0);
  mma_tile<2,2>(Alds + 0*(64*32), Blds + 0*(64*32), acc, wm, wn, quad, t16);
  asm volatile("s_waitcnt vmcnt(0)" ::: "memory");
  __builtin_amdgcn_s_barrier();
  __builtin_amdgcn_sched_barrier(0);
  mma_tile<2,2>(Alds + 1*(64*32), Blds + 1*(64*32), acc, wm, wn, quad, t16);
#pragma unroll
  for (int mi = 0; mi < 2; ++mi)
#pragma unroll
    for (int ni = 0; ni < 2; ++ni)
#pragma unroll
      for (int r = 0; r < 4; ++r){
        long grow = row0 + wm*32 + mi*16 + quad*4 + r;
        int  gcol = col0 + wn*32 + ni*16 + t16;
        P[grow*256 + gcol] = acc[mi][ni][r];
      }
}

// ---------------------------------------------------------------------------
// K4: out[bt][d] = sum_n Xs[bt][n]*C[d][n] + sum_e u[bt][e]*Dm[d][e], fp32 out.
// Proven round-4 config: tile 128x256, grid 512, 3-buffer pipeline, vmcnt(6).
// ---------------------------------------------------------------------------
extern "C" __global__ __launch_bounds__(256, 2) void k_gemm_out(
    const bf16raw* __restrict__ Xs, const bf16raw* __restrict__ u_bf,
    const bf16raw* __restrict__ C_bf, const bf16raw* __restrict__ Dm_bf,
    float* __restrict__ out){
  __shared__ __align__(16) bf16raw Alds[3*128*32];   // 24 KB
  __shared__ __align__(16) bf16raw Blds[3*256*32];   // 48 KB
  int tid = threadIdx.x, wave = tid >> 6, lane = tid & 63;
  int quad = lane >> 4, t16 = lane & 15;
  int wm = wave >> 1, wn = wave & 1;                 // wave tile 64x128
  int id  = blockIdx.y * gridDim.x + blockIdx.x;
  int sid = (id & 7) * 64 + (id >> 3);
  long row0 = (long)(sid >> 2) * 128;
  int  col0 = (sid & 3) * 256;
  f32x4 acc[4][8] = {};

  auto stage = [&](int s, int buf){
    if (s < 4){
      stage_async<2>(Xs,   128, row0, s*32, Alds + buf*(128*32), wave, lane);
      stage_async<4>(C_bf, 128, col0, s*32, Blds + buf*(256*32), wave, lane);
    } else {
      stage_async<2>(u_bf,  1024, row0, (s-4)*32, Alds + buf*(128*32), wave, lane);
      stage_async<4>(Dm_bf, 1024, col0, (s-4)*32, Blds + buf*(256*32), wave, lane);
    }
  };

  stage(0, 0);
  stage(1, 1);
  int rd = 0;                                        // rd = s % 3
  for (int s = 0; s < 34; ++s){
    asm volatile("s_waitcnt vmcnt(6)" ::: "memory");
    __builtin_amdgcn_s_barrier();
    __builtin_amdgcn_sched_barrier(0);
    int st = rd >= 1 ? rd - 1 : 2;                   // (s+2)%3
    stage(s + 2, st);
    __builtin_amdgcn_s_setprio(1);
    mma_tile<4,8>(Alds + rd*(128*32), Blds + rd*(256*32), acc, wm, wn, quad, t16);
    __builtin_amdgcn_s_setprio(0);
    rd = rd < 2 ? rd + 1 : 0;
  }
  asm volatile("s_waitcnt vmcnt(6)" ::: "memory");
  __builtin_amdgcn_s_barrier();
  __builtin_amdgcn_sched_barrier(0);
  mma_tile<4,8>(Alds + 1*(128*32), Blds + 1*(256*32), acc, wm, wn, quad, t16);
  asm volatile("s_waitcnt vmcnt(0)" ::: "memory");
  __builtin_amdgcn_s_barrier();
  __builtin_amdgcn_sched_barrier(0);
  mma_tile<4,8>(Alds + 2*(128*32), Blds + 2*(256*32), acc, wm, wn, quad, t16);
#pragma unroll
  for (int mi = 0; mi < 4; ++mi)
#pragma unroll
    for (int ni = 0; ni < 8; ++ni)
#pragma unroll
      for (int r = 0; r < 4; ++r){
        long grow = row0 + wm*64 + mi*16 + quad*4 + r;
        int  gcol = col0 + wn*128 + ni*16 + t16;
        out[grow*1024 + gcol] = acc[mi][ni][r];
      }
}

// ---------------------------------------------------------------------------
// Coefs from a P row (shared by phase A and C).
// ---------------------------------------------------------------------------
__device__ __forceinline__ void coef_row(const float* __restrict__ r, int m,
                                         float bo, float bz, float bb0, float bb1,
                                         float& p, float& q, float& fz, float& fy){
  float wo = r[m]       + bo;
  float wz = r[64 + m]  + bz;
  fz = r[128 + m] + bb0;
  fy = r[192 + m] + bb1;
  float sp = (wo > 20.f) ? wo : log1pf(expf(wo));
  float omega = fminf(fmaxf(sp, 1e-4f), 100.f);
  float A = omega * omega;
  float S = 1.f / (1.f + DTC*DTC*A);
  float zeta = 1.f / (1.f + expf(-wz));
  p = (1.f - zeta) * S;
  q = p * DTC * A;
}

// ---------------------------------------------------------------------------
// Device-scope grid barrier (G16 pattern: release fence + device atomicAdd;
// acquire via __hip_atomic_load AGENT + fence). All 512 blocks provably
// co-resident: 256 thr, ~6 KB LDS, <128 VGPR -> >=2 blocks/CU.
// Counters re-zeroed per iteration by hipMemsetAsync on-stream.
// ---------------------------------------------------------------------------
__device__ __forceinline__ void grid_barrier(unsigned* cnt, unsigned nblk, int tid){
  __syncthreads();
  if (tid == 0){
    __threadfence();                                // release: prior stores visible
    atomicAdd(cnt, 1u);
    while (__hip_atomic_load(cnt, __ATOMIC_ACQUIRE, __HIP_MEMORY_SCOPE_AGENT) < nblk)
      __builtin_amdgcn_s_sleep(2);
  }
  __syncthreads();
  __threadfence();                                  // acquire: invalidate stale lines
}

// ---------------------------------------------------------------------------
// Fused scan: ONE kernel, 512 blocks x 256 thr, 2 internal grid barriers.
// Phase A (block=chunk c of 512, 8 steps): chunk summary CM/CV.
// Phase B (blocks 0..255, block=series s): scan 512 chunks with 256 threads
//   via pairwise pre-combine + 8-round Kogge-Stone + exclusive shift; emits
//   XIn[chunk] = state entering chunk (x0 = 0).
// Phase C (block=chunk c): recompute coefs from P, apply chunk, write Xs.
// ---------------------------------------------------------------------------
extern "C" __global__ __launch_bounds__(256) void k_scan_fused(
    const float* __restrict__ P, const float* __restrict__ b_om,
    const float* __restrict__ b_ze, const float* __restrict__ b_B,
    float4* __restrict__ CM, float2* __restrict__ CV,
    float2* __restrict__ XIn, bf16raw* __restrict__ Xs,
    unsigned* __restrict__ cnt){
  __shared__ float sm[6][256];
  int tid = threadIdx.x, c = blockIdx.x;
  int b = tid >> 6, m = tid & 63;
  float bo = b_om[m], bz = b_ze[m], bb0 = b_B[m], bb1 = b_B[64 + m];

  { // ---- Phase A: chunk summary (8 steps) ----
    const float* row = P + ((size_t)b*4096 + c*8) * 256;
    float m00=1.f, m01=0.f, m10=0.f, m11=0.f, vz=0.f, vy=0.f;
#pragma unroll
    for (int t = 0; t < 8; ++t){
      float p, q, fz, fy;
      coef_row(row + t*256, m, bo, bz, bb0, bb1, p, q, fz, fy);
      float nvz = p*vz - q*vy + fz;
      float nvy = DTC*p*vz + p*vy + fy;
      vz = nvz; vy = nvy;
      float n00 = p*m00 - q*m10;
      float n01 = p*m01 - q*m11;
      float n10 = DTC*p*m00 + p*m10;
      float n11 = DTC*p*m01 + p*m11;
      m00=n00; m01=n01; m10=n10; m11=n11;
    }
    CM[(size_t)c*256 + tid] = make_float4(m00, m01, m10, m11);
    CV[(size_t)c*256 + tid] = make_float2(vz, vy);
  }

  grid_barrier(cnt, 512u, tid);                     // all CM/CV ready

  if (c < 256){ // ---- Phase B: per-series scan (block = series s = c) ----
    int s = c, t = tid;
    float4 Ma = CM[(size_t)(2*t)*256 + s];   float2 Va = CV[(size_t)(2*t)*256 + s];
    float4 Mb = CM[(size_t)(2*t+1)*256 + s]; float2 Vb = CV[(size_t)(2*t+1)*256 + s];
    // super-chunk = chunk(2t+1) ∘ chunk(2t)
    float m00 = Mb.x*Ma.x + Mb.y*Ma.z;
    float m01 = Mb.x*Ma.y + Mb.y*Ma.w;
    float m10 = Mb.z*Ma.x + Mb.w*Ma.z;
    float m11 = Mb.z*Ma.y + Mb.w*Ma.w;
    float vz  = Mb.x*Va.x + Mb.y*Va.y + Vb.x;
    float vy  = Mb.z*Va.x + Mb.w*Va.y + Vb.y;
#pragma unroll
    for (int off = 1; off < 256; off <<= 1){
      sm[0][t]=m00; sm[1][t]=m01; sm[2][t]=m10; sm[3][t]=m11; sm[4][t]=vz; sm[5][t]=vy;
      __syncthreads();
      if (t >= off){
        int p = t - off;
        float e00=sm[0][p], e01=sm[1][p], e10=sm[2][p], e11=sm[3][p];
        float evz=sm[4][p], evy=sm[5][p];
        float n00 = m00*e00 + m01*e10;
        float n01 = m00*e01 + m01*e11;
        float n10 = m10*e00 + m11*e10;
        float n11 = m10*e01 + m11*e11;
        float nvz = m00*evz + m01*evy + vz;
        float nvy = m10*evz + m11*evy + vy;
        m00=n00; m01=n01; m10=n10; m11=n11; vz=nvz; vy=nvy;
      }
      __syncthreads();
    }
    // inclusive over super-chunks [0..t] -> exclusive via shift
    sm[4][t]=vz; sm[5][t]=vy;
    __syncthreads();
    float evz = (t > 0) ? sm[4][t-1] : 0.f;
    float evy = (t > 0) ? sm[5][t-1] : 0.f;
    // XIn[2t] = state entering chunk 2t; XIn[2t+1] = chunk(2t) applied to it
    XIn[(size_t)(2*t)*256 + s]   = make_float2(evz, evy);
    XIn[(size_t)(2*t+1)*256 + s] = make_float2(Ma.x*evz + Ma.y*evy + Va.x,
                                               Ma.z*evz + Ma.w*evy + Va.y);
  }

  grid_barrier(cnt + 1, 512u, tid);                 // all XIn ready

  { // ---- Phase C: apply chunk, emit Xs (bf16) ----
    float2 x0 = XIn[(size_t)c*256 + tid];
    float xz = x0.x, xy = x0.y;
    const float* row = P + ((size_t)b*4096 + c*8) * 256;
    bf16raw* xp = Xs + ((size_t)b*4096 + c*8) * 128 + m;
#pragma unroll
    for (int t = 0; t < 8; ++t){
      float p, q, fz, fy;
      coef_row(row + t*256, m, bo, bz, bb0, bb1, p, q, fz, fy);
      float nz = p*xz - q*xy + fz;
      float ny = DTC*p*xz + p*xy + fy;
      xz = nz; xy = ny;
      xp[t*128]      = f2bf(xz);   // z part: n = m
      xp[t*128 + 64] = f2bf(xy);   // y part: n = 64 + m
    }
  }
}

// ---------------------------------------------------------------------------
extern "C" void kernel_launch(void* const* d_in, const int* in_sizes, int n_in,
                              void* d_out, int out_size, void* d_ws, size_t ws_size,
                              hipStream_t stream){
  const float* u   = (const float*)d_in[0];
  const float* Wom = (const float*)d_in[1];
  const float* bom = (const float*)d_in[2];
  const float* Wze = (const float*)d_in[3];
  const float* bze = (const float*)d_in[4];
  const float* WB  = (const float*)d_in[5];
  const float* bB  = (const float*)d_in[6];
  const float* Cm  = (const float*)d_in[7];
  const float* Dm  = (const float*)d_in[8];
  float* out = (float*)d_out;

  char* ws = (char*)d_ws;
  size_t off = 0;
  bf16raw* u_bf  = (bf16raw*)(ws + off); off += (size_t)16777216*2;    // 32 MB
  bf16raw* Wcat  = (bf16raw*)(ws + off); off += (size_t)262144*2;      // 512 KB
  bf16raw* C_bf  = (bf16raw*)(ws + off); off += (size_t)131072*2;      // 256 KB
  bf16raw* Dm_bf = (bf16raw*)(ws + off); off += (size_t)1048576*2;     // 2 MB
  float*   P     = (float*)  (ws + off); off += (size_t)16384*256*4;   // 16 MB
  bf16raw* Xs    = (bf16raw*)(ws + off); off += (size_t)16384*128*2;   // 4 MB
  float4*  CMw   = (float4*) (ws + off); off += (size_t)512*256*16;    // 2 MB
  float2*  CVw   = (float2*) (ws + off); off += (size_t)512*256*8;     // 1 MB
  float2*  XIn   = (float2*) (ws + off); off += (size_t)512*256*8;     // 1 MB
  unsigned* cnt  = (unsigned*)(ws + off); off += 256;                  // 2 barrier counters

  hipMemsetAsync(cnt, 0, 8, stream);
  k_prep      <<<2048, 256, 0, stream>>>(u, Wom, Wze, WB, Cm, Dm, u_bf, Wcat, C_bf, Dm_bf);
  k_gemm_p    <<<dim3(4, 256), 256, 0, stream>>>(u_bf, Wcat, P);
  k_scan_fused<<<512, 256, 0, stream>>>(P, bom, bze, bB, CMw, CVw, XIn, Xs, cnt);
  k_gemm_out  <<<dim3(4, 128), 256, 0, stream>>>(Xs, u_bf, C_bf, Dm_bf, out);
}

// Round 9
// 222.692 us; speedup vs baseline: 1.6645x; 1.6645x over previous
//
#include <hip/hip_runtime.h>
#include <hip/hip_bf16.h>
#include <math.h>

#define DTC 0.01f

typedef __attribute__((ext_vector_type(8))) short short8;   // 8 x bf16 (4 VGPRs)
typedef __attribute__((ext_vector_type(4))) float f32x4;    // MFMA C/D
typedef unsigned short bf16raw;

__device__ __forceinline__ bf16raw f2bf(float f){
  union { unsigned u; float f; } v; v.f = f;
  unsigned r = v.u + 0x7FFF + ((v.u >> 16) & 1u);   // round-to-nearest-even
  return (bf16raw)(r >> 16);
}

// Load 8 consecutive fp32, round to 8 bf16.
__device__ __forceinline__ short8 ld8f(const float* __restrict__ p){
  float4 a = *(const float4*)p;
  float4 b = *(const float4*)(p + 4);
  short8 r;
  r[0] = (short)f2bf(a.x); r[1] = (short)f2bf(a.y);
  r[2] = (short)f2bf(a.z); r[3] = (short)f2bf(a.w);
  r[4] = (short)f2bf(b.x); r[5] = (short)f2bf(b.y);
  r[6] = (short)f2bf(b.z); r[7] = (short)f2bf(b.w);
  return r;
}

// ---------------------------------------------------------------------------
// Async-stage ITERS*16 rows x 32 bf16 -> LDS [row][32], T2-swizzled.
// LDS dest linear (global_load_lds HW requirement); 16B k-slot permuted on
// the GLOBAL side (rule #21): slot (lane&3) holds k-chunk (lane&3)^((lane>>3)&3).
// Reader applies the same involution -> 2-way (free) bank access.
// ---------------------------------------------------------------------------
template<int ITERS>
__device__ __forceinline__ void stage_async(const bf16raw* __restrict__ src, long ld,
                                            long row0, int k0, bf16raw* lds,
                                            int wave, int lane){
  int kchunk = (lane & 3) ^ ((lane >> 3) & 3);
#pragma unroll
  for (int i = 0; i < ITERS; ++i){
    int r0 = (wave*ITERS + i) * 16;
    long row = row0 + r0 + (lane >> 2);
    const bf16raw* gp = src + row*ld + k0 + kchunk*8;
    bf16raw* lp = lds + r0*32;
    __builtin_amdgcn_global_load_lds((const __attribute__((address_space(1))) void*)gp,
                                     (__attribute__((address_space(3))) void*)lp,
                                     16, 0, 0);
  }
}

// One BK=32 step: MI A-frags + NI B-frags (ds_read_b128, swizzled slot) + MI*NI MFMA.
template<int MI, int NI>
__device__ __forceinline__ void mma_tile(const bf16raw* Alds, const bf16raw* Blds,
                                         f32x4 acc[MI][NI], int wm, int wn, int quad, int t16){
  short8 af[MI], bfr[NI];
  int sw = (quad ^ ((t16 >> 1) & 3)) * 8;   // physical 16B slot for this lane's rows
#pragma unroll
  for (int mi = 0; mi < MI; ++mi)
    af[mi] = *(const short8*)(Alds + (wm*(MI*16) + mi*16 + t16)*32 + sw);
#pragma unroll
  for (int ni = 0; ni < NI; ++ni)
    bfr[ni] = *(const short8*)(Blds + (wn*(NI*16) + ni*16 + t16)*32 + sw);
#pragma unroll
  for (int mi = 0; mi < MI; ++mi)
#pragma unroll
    for (int ni = 0; ni < NI; ++ni)
      acc[mi][ni] = __builtin_amdgcn_mfma_f32_16x16x32_bf16(af[mi], bfr[ni], acc[mi][ni], 0, 0, 0);
}

// ---------------------------------------------------------------------------
// Prep: fp32 -> bf16 for u, [W_omega|W_zeta|W_B] (concat), C, D_mat.
// Grid-stride, 2048 blocks.
// ---------------------------------------------------------------------------
extern "C" __global__ void k_prep(const float* __restrict__ u,
    const float* __restrict__ Wom, const float* __restrict__ Wze,
    const float* __restrict__ WB, const float* __restrict__ Cm,
    const float* __restrict__ Dm, bf16raw* __restrict__ u_bf,
    bf16raw* __restrict__ Wcat, bf16raw* __restrict__ C_bf,
    bf16raw* __restrict__ Dm_bf){
  for (long g = (long)blockIdx.x * 256 + threadIdx.x; g < 2277376;
       g += (long)gridDim.x * 256){
    const float* src; bf16raw* dst; long o;
    if      (g < 2097152){ src = u;   dst = u_bf;          o = g; }
    else if (g < 2105344){ src = Wom; dst = Wcat;          o = g - 2097152; }
    else if (g < 2113536){ src = Wze; dst = Wcat + 65536;  o = g - 2105344; }
    else if (g < 2129920){ src = WB;  dst = Wcat + 131072; o = g - 2113536; }
    else if (g < 2146304){ src = Cm;  dst = C_bf;          o = g - 2129920; }
    else                 { src = Dm;  dst = Dm_bf;         o = g - 2146304; }
    *(short8*)(dst + o*8) = ld8f(src + o*8);
  }
}

// ---------------------------------------------------------------------------
// K1: P[bt][n] = sum_d u[bt][d] * Wcat[n][d]  (16384 x 256, K=1024), fp32 out.
// Tile 64x64, 1024 blocks (4/CU). 3-buffer single-barrier pipeline.
// ---------------------------------------------------------------------------
extern "C" __global__ __launch_bounds__(256, 4) void k_gemm_p(
    const bf16raw* __restrict__ u_bf, const bf16raw* __restrict__ Wcat,
    float* __restrict__ P){
  __shared__ __align__(16) bf16raw Alds[3*64*32];    // 12 KB
  __shared__ __align__(16) bf16raw Blds[3*64*32];    // 12 KB
  int tid = threadIdx.x, wave = tid >> 6, lane = tid & 63;
  int quad = lane >> 4, t16 = lane & 15;
  int wm = wave >> 1, wn = wave & 1;                 // wave tile 32x32
  int id  = blockIdx.y * gridDim.x + blockIdx.x;
  int sid = (id & 7) * 128 + (id >> 3);
  long row0 = (long)(sid >> 2) * 64;
  int  col0 = (sid & 3) * 64;
  f32x4 acc[2][2] = {};

  auto stage = [&](int kt, int buf){
    stage_async<1>(u_bf, 1024, row0, kt*32, Alds + buf*(64*32), wave, lane);
    stage_async<1>(Wcat, 1024, col0, kt*32, Blds + buf*(64*32), wave, lane);
  };

  stage(0, 0);
  stage(1, 1);
  int rd = 0;                                        // rd = s % 3
  for (int s = 0; s < 30; ++s){
    asm volatile("s_waitcnt vmcnt(2)" ::: "memory");
    __builtin_amdgcn_s_barrier();
    __builtin_amdgcn_sched_barrier(0);
    int st = rd >= 1 ? rd - 1 : 2;                   // (s+2)%3
    stage(s + 2, st);
    __builtin_amdgcn_s_setprio(1);
    mma_tile<2,2>(Alds + rd*(64*32), Blds + rd*(64*32), acc, wm, wn, quad, t16);
    __builtin_amdgcn_s_setprio(0);
    rd = rd < 2 ? rd + 1 : 0;
  }
  asm volatile("s_waitcnt vmcnt(2)" ::: "memory");
  __builtin_amdgcn_s_barrier();
  __builtin_amdgcn_sched_barrier(0);
  mma_tile<2,2>(Alds + 0*(64*32), Blds + 0*(64*32), acc, wm, wn, quad, t16);
  asm volatile("s_waitcnt vmcnt(0)" ::: "memory");
  __builtin_amdgcn_s_barrier();
  __builtin_amdgcn_sched_barrier(0);
  mma_tile<2,2>(Alds + 1*(64*32), Blds + 1*(64*32), acc, wm, wn, quad, t16);
#pragma unroll
  for (int mi = 0; mi < 2; ++mi)
#pragma unroll
    for (int ni = 0; ni < 2; ++ni)
#pragma unroll
      for (int r = 0; r < 4; ++r){
        long grow = row0 + wm*32 + mi*16 + quad*4 + r;
        int  gcol = col0 + wn*32 + ni*16 + t16;
        P[grow*256 + gcol] = acc[mi][ni][r];
      }
}

// ---------------------------------------------------------------------------
// K4: out[bt][d] = sum_n Xs[bt][n]*C[d][n] + sum_e u[bt][e]*Dm[d][e], fp32 out.
// NEW: tile 256x256, 512 threads (8 waves, wave tile 64x128), grid 256
// (1 block/CU, 8 waves/CU — same wave count as the 128x256 config).
// Halves L2 operand traffic: B re-read 128->64x, A unchanged 4x
// (theory: operand-delivery-bound at 27 B/cy/CU, not MFMA-bound).
// Same proven 3-buffer single-barrier pipeline; 4 loads/wave/stage -> vmcnt(4).
// LDS 96 KB.
// ---------------------------------------------------------------------------
extern "C" __global__ __launch_bounds__(512, 1) void k_gemm_out(
    const bf16raw* __restrict__ Xs, const bf16raw* __restrict__ u_bf,
    const bf16raw* __restrict__ C_bf, const bf16raw* __restrict__ Dm_bf,
    float* __restrict__ out){
  __shared__ __align__(16) bf16raw Alds[3*256*32];   // 48 KB
  __shared__ __align__(16) bf16raw Blds[3*256*32];   // 48 KB
  int tid = threadIdx.x, wave = tid >> 6, lane = tid & 63;
  int quad = lane >> 4, t16 = lane & 15;
  int wm = wave >> 1, wn = wave & 1;                 // 4x2 waves, tile 64x128
  // XCD-aware swizzle: 256 blocks, 8 XCDs x 32 consecutive sids each
  // (8 row panels x 4 col tiles -> u slice 4 MB = L2-resident per XCD).
  int id  = blockIdx.y * gridDim.x + blockIdx.x;
  int sid = (id & 7) * 32 + (id >> 3);
  long row0 = (long)(sid >> 2) * 256;
  int  col0 = (sid & 3) * 256;
  f32x4 acc[4][8] = {};

  auto stage = [&](int s, int buf){
    if (s < 4){
      stage_async<2>(Xs,   128, row0, s*32, Alds + buf*(256*32), wave, lane);
      stage_async<2>(C_bf, 128, col0, s*32, Blds + buf*(256*32), wave, lane);
    } else {
      stage_async<2>(u_bf,  1024, row0, (s-4)*32, Alds + buf*(256*32), wave, lane);
      stage_async<2>(Dm_bf, 1024, col0, (s-4)*32, Blds + buf*(256*32), wave, lane);
    }
  };

  stage(0, 0);
  stage(1, 1);
  int rd = 0;                                        // rd = s % 3
  for (int s = 0; s < 34; ++s){
    asm volatile("s_waitcnt vmcnt(4)" ::: "memory"); // own stage-s loads landed
    __builtin_amdgcn_s_barrier();                    // all waves' stage-s landed;
    __builtin_amdgcn_sched_barrier(0);               // buf (s-1)%3 fully consumed
    int st = rd >= 1 ? rd - 1 : 2;                   // (s+2)%3
    stage(s + 2, st);                                // issue early, before MFMA
    __builtin_amdgcn_s_setprio(1);
    mma_tile<4,8>(Alds + rd*(256*32), Blds + rd*(256*32), acc, wm, wn, quad, t16);
    __builtin_amdgcn_s_setprio(0);
    rd = rd < 2 ? rd + 1 : 0;
  }
  asm volatile("s_waitcnt vmcnt(4)" ::: "memory");   // s=34 reads buf 1
  __builtin_amdgcn_s_barrier();
  __builtin_amdgcn_sched_barrier(0);
  mma_tile<4,8>(Alds + 1*(256*32), Blds + 1*(256*32), acc, wm, wn, quad, t16);
  asm volatile("s_waitcnt vmcnt(0)" ::: "memory");   // s=35 reads buf 2
  __builtin_amdgcn_s_barrier();
  __builtin_amdgcn_sched_barrier(0);
  mma_tile<4,8>(Alds + 2*(256*32), Blds + 2*(256*32), acc, wm, wn, quad, t16);
#pragma unroll
  for (int mi = 0; mi < 4; ++mi)
#pragma unroll
    for (int ni = 0; ni < 8; ++ni)
#pragma unroll
      for (int r = 0; r < 4; ++r){
        long grow = row0 + wm*64 + mi*16 + quad*4 + r;
        int  gcol = col0 + wn*128 + ni*16 + t16;
        out[grow*1024 + gcol] = acc[mi][ni][r];
      }
}

// ---------------------------------------------------------------------------
// scanA: coef + chunk summary. 256 chunks x 16 steps; block = chunk;
// thread tid = (b,m) series. Reads P, writes per-chunk CM/CV.
// (r6-measured config, 214.3 us.)
// ---------------------------------------------------------------------------
extern "C" __global__ __launch_bounds__(256) void k_scanA(
    const float* __restrict__ P, const float* __restrict__ b_om,
    const float* __restrict__ b_ze, const float* __restrict__ b_B,
    float4* __restrict__ CM, float2* __restrict__ CV){
  int tid = threadIdx.x, c = blockIdx.x;
  int b = tid >> 6, m = tid & 63;
  float bo = b_om[m], bz = b_ze[m], bb0 = b_B[m], bb1 = b_B[64 + m];
  const float* row = P + ((size_t)b*4096 + c*16) * 256;
  float m00=1.f, m01=0.f, m10=0.f, m11=0.f, vz=0.f, vy=0.f;
#pragma unroll 4
  for (int t = 0; t < 16; ++t){
    const float* r = row + t*256;
    float wo = r[m]       + bo;
    float wz = r[64 + m]  + bz;
    float fz = r[128 + m] + bb0;
    float fy = r[192 + m] + bb1;
    float sp = (wo > 20.f) ? wo : log1pf(expf(wo));
    float omega = fminf(fmaxf(sp, 1e-4f), 100.f);
    float A = omega * omega;
    float S = 1.f / (1.f + DTC*DTC*A);
    float zeta = 1.f / (1.f + expf(-wz));
    float p = (1.f - zeta) * S;
    float q = p * DTC * A;
    float nvz = p*vz - q*vy + fz;
    float nvy = DTC*p*vz + p*vy + fy;
    vz = nvz; vy = nvy;
    float n00 = p*m00 - q*m10;
    float n01 = p*m01 - q*m11;
    float n10 = DTC*p*m00 + p*m10;
    float n11 = DTC*p*m01 + p*m11;
    m00=n00; m01=n01; m10=n10; m11=n11;
  }
  CM[c*256 + tid] = make_float4(m00, m01, m10, m11);
  CV[c*256 + tid] = make_float2(vz, vy);
}

// ---------------------------------------------------------------------------
// scanB: Kogge-Stone scan over the 256 chunk summaries, one block per
// series. XIn[c] = state entering chunk c (x0 = 0).
// ---------------------------------------------------------------------------
extern "C" __global__ __launch_bounds__(256) void k_scanB(
    const float4* __restrict__ CM, const float2* __restrict__ CV,
    float2* __restrict__ XIn){
  __shared__ float sm[6][256];
  int s = blockIdx.x;            // series (b*64+m)
  int c = threadIdx.x;           // chunk
  float4 Mv = CM[(size_t)c*256 + s];
  float2 Vv = CV[(size_t)c*256 + s];
  float m00=Mv.x, m01=Mv.y, m10=Mv.z, m11=Mv.w, vz=Vv.x, vy=Vv.y;
#pragma unroll
  for (int off = 1; off < 256; off <<= 1){
    sm[0][c]=m00; sm[1][c]=m01; sm[2][c]=m10; sm[3][c]=m11; sm[4][c]=vz; sm[5][c]=vy;
    __syncthreads();
    if (c >= off){
      int p = c - off;
      float e00=sm[0][p], e01=sm[1][p], e10=sm[2][p], e11=sm[3][p];
      float evz=sm[4][p], evy=sm[5][p];
      float n00 = m00*e00 + m01*e10;
      float n01 = m00*e01 + m01*e11;
      float n10 = m10*e00 + m11*e10;
      float n11 = m10*e01 + m11*e11;
      float nvz = m00*evz + m01*evy + vz;
      float nvy = m10*evz + m11*evy + vy;
      m00=n00; m01=n01; m10=n10; m11=n11; vz=nvz; vy=nvy;
    }
    __syncthreads();
  }
  if (c < 255) XIn[(size_t)(c+1)*256 + s] = make_float2(vz, vy);
  if (c == 0)  XIn[s] = make_float2(0.f, 0.f);
}

// ---------------------------------------------------------------------------
// scanC: pure streaming — read chunk-start state from XIn, recompute coefs
// from P (bit-identical to scanA's), apply 16-step chunk, write Xs (bf16).
// ---------------------------------------------------------------------------
extern "C" __global__ __launch_bounds__(256) void k_scanC(
    const float* __restrict__ P, const float* __restrict__ b_om,
    const float* __restrict__ b_ze, const float* __restrict__ b_B,
    const float2* __restrict__ XIn, bf16raw* __restrict__ Xs){
  int tid = threadIdx.x, c = blockIdx.x;
  int b = tid >> 6, m = tid & 63;
  float2 x0 = XIn[(size_t)c*256 + tid];
  float xz = x0.x, xy = x0.y;
  float bo = b_om[m], bz = b_ze[m], bb0 = b_B[m], bb1 = b_B[64 + m];
  const float* row = P + ((size_t)b*4096 + c*16) * 256;
  bf16raw* xp = Xs + ((size_t)b*4096 + c*16) * 128 + m;
#pragma unroll 4
  for (int t = 0; t < 16; ++t){
    const float* r = row + t*256;
    float wo = r[m]       + bo;
    float wz = r[64 + m]  + bz;
    float fz = r[128 + m] + bb0;
    float fy = r[192 + m] + bb1;
    float sp = (wo > 20.f) ? wo : log1pf(expf(wo));
    float omega = fminf(fmaxf(sp, 1e-4f), 100.f);
    float A = omega * omega;
    float S = 1.f / (1.f + DTC*DTC*A);
    float zeta = 1.f / (1.f + expf(-wz));
    float p = (1.f - zeta) * S;
    float q = p * DTC * A;
    float nz = p*xz - q*xy + fz;
    float ny = DTC*p*xz + p*xy + fy;
    xz = nz; xy = ny;
    xp[t*128]      = f2bf(xz);   // z part: n = m
    xp[t*128 + 64] = f2bf(xy);   // y part: n = 64 + m
  }
}

// ---------------------------------------------------------------------------
extern "C" void kernel_launch(void* const* d_in, const int* in_sizes, int n_in,
                              void* d_out, int out_size, void* d_ws, size_t ws_size,
                              hipStream_t stream){
  const float* u   = (const float*)d_in[0];
  const float* Wom = (const float*)d_in[1];
  const float* bom = (const float*)d_in[2];
  const float* Wze = (const float*)d_in[3];
  const float* bze = (const float*)d_in[4];
  const float* WB  = (const float*)d_in[5];
  const float* bB  = (const float*)d_in[6];
  const float* Cm  = (const float*)d_in[7];
  const float* Dm  = (const float*)d_in[8];
  float* out = (float*)d_out;

  char* ws = (char*)d_ws;
  size_t off = 0;
  bf16raw* u_bf  = (bf16raw*)(ws + off); off += (size_t)16777216*2;    // 32 MB
  bf16raw* Wcat  = (bf16raw*)(ws + off); off += (size_t)262144*2;      // 512 KB
  bf16raw* C_bf  = (bf16raw*)(ws + off); off += (size_t)131072*2;      // 256 KB
  bf16raw* Dm_bf = (bf16raw*)(ws + off); off += (size_t)1048576*2;     // 2 MB
  float*   P     = (float*)  (ws + off); off += (size_t)16384*256*4;   // 16 MB
  bf16raw* Xs    = (bf16raw*)(ws + off); off += (size_t)16384*128*2;   // 4 MB
  float4*  CMw   = (float4*) (ws + off); off += (size_t)256*256*16;    // 1 MB
  float2*  CVw   = (float2*) (ws + off); off += (size_t)256*256*8;     // 512 KB
  float2*  XIn   = (float2*) (ws + off); off += (size_t)256*256*8;     // 512 KB

  k_prep    <<<2048, 256, 0, stream>>>(u, Wom, Wze, WB, Cm, Dm, u_bf, Wcat, C_bf, Dm_bf);
  k_gemm_p  <<<dim3(4, 256), 256, 0, stream>>>(u_bf, Wcat, P);
  k_scanA   <<<256, 256, 0, stream>>>(P, bom, bze, bB, CMw, CVw);
  k_scanB   <<<256, 256, 0, stream>>>(CMw, CVw, XIn);
  k_scanC   <<<256, 256, 0, stream>>>(P, bom, bze, bB, XIn, Xs);
  k_gemm_out<<<dim3(4, 64), 512, 0, stream>>>(Xs, u_bf, C_bf, Dm_bf, out);
}

// Round 10
// 213.480 us; speedup vs baseline: 1.7364x; 1.0431x over previous
//
#include <hip/hip_runtime.h>
#include <hip/hip_bf16.h>
#include <math.h>

#define DTC 0.01f

typedef __attribute__((ext_vector_type(8))) short short8;   // 8 x bf16 (4 VGPRs)
typedef __attribute__((ext_vector_type(4))) float f32x4;    // MFMA C/D
typedef unsigned short bf16raw;

__device__ __forceinline__ bf16raw f2bf(float f){
  union { unsigned u; float f; } v; v.f = f;
  unsigned r = v.u + 0x7FFF + ((v.u >> 16) & 1u);   // round-to-nearest-even
  return (bf16raw)(r >> 16);
}

// Load 8 consecutive fp32, round to 8 bf16.
__device__ __forceinline__ short8 ld8f(const float* __restrict__ p){
  float4 a = *(const float4*)p;
  float4 b = *(const float4*)(p + 4);
  short8 r;
  r[0] = (short)f2bf(a.x); r[1] = (short)f2bf(a.y);
  r[2] = (short)f2bf(a.z); r[3] = (short)f2bf(a.w);
  r[4] = (short)f2bf(b.x); r[5] = (short)f2bf(b.y);
  r[6] = (short)f2bf(b.z); r[7] = (short)f2bf(b.w);
  return r;
}

// ---------------------------------------------------------------------------
// Async-stage ITERS*16 rows x 32 bf16 -> LDS [row][32], T2-swizzled
// (wave-based mapping, for 256-thread GEMM kernels).
// ---------------------------------------------------------------------------
template<int ITERS>
__device__ __forceinline__ void stage_async(const bf16raw* __restrict__ src, long ld,
                                            long row0, int k0, bf16raw* lds,
                                            int wave, int lane){
  int kchunk = (lane & 3) ^ ((lane >> 3) & 3);
#pragma unroll
  for (int i = 0; i < ITERS; ++i){
    int r0 = (wave*ITERS + i) * 16;
    long row = row0 + r0 + (lane >> 2);
    const bf16raw* gp = src + row*ld + k0 + kchunk*8;
    bf16raw* lp = lds + r0*32;
    __builtin_amdgcn_global_load_lds((const __attribute__((address_space(1))) void*)gp,
                                     (__attribute__((address_space(3))) void*)lp,
                                     16, 0, 0);
  }
}

// One BK=32 step: MI A-frags + NI B-frags (ds_read_b128, swizzled slot) + MI*NI MFMA.
template<int MI, int NI>
__device__ __forceinline__ void mma_tile(const bf16raw* Alds, const bf16raw* Blds,
                                         f32x4 acc[MI][NI], int wm, int wn, int quad, int t16){
  short8 af[MI], bfr[NI];
  int sw = (quad ^ ((t16 >> 1) & 3)) * 8;   // physical 16B slot for this lane's rows
#pragma unroll
  for (int mi = 0; mi < MI; ++mi)
    af[mi] = *(const short8*)(Alds + (wm*(MI*16) + mi*16 + t16)*32 + sw);
#pragma unroll
  for (int ni = 0; ni < NI; ++ni)
    bfr[ni] = *(const short8*)(Blds + (wn*(NI*16) + ni*16 + t16)*32 + sw);
#pragma unroll
  for (int mi = 0; mi < MI; ++mi)
#pragma unroll
    for (int ni = 0; ni < NI; ++ni)
      acc[mi][ni] = __builtin_amdgcn_mfma_f32_16x16x32_bf16(af[mi], bfr[ni], acc[mi][ni], 0, 0, 0);
}

// ---------------------------------------------------------------------------
// Prep: fp32 -> bf16 for u, [W_omega|W_zeta|W_B] (concat), C, D_mat.
// Grid-stride, 2048 blocks.
// ---------------------------------------------------------------------------
extern "C" __global__ void k_prep(const float* __restrict__ u,
    const float* __restrict__ Wom, const float* __restrict__ Wze,
    const float* __restrict__ WB, const float* __restrict__ Cm,
    const float* __restrict__ Dm, bf16raw* __restrict__ u_bf,
    bf16raw* __restrict__ Wcat, bf16raw* __restrict__ C_bf,
    bf16raw* __restrict__ Dm_bf){
  for (long g = (long)blockIdx.x * 256 + threadIdx.x; g < 2277376;
       g += (long)gridDim.x * 256){
    const float* src; bf16raw* dst; long o;
    if      (g < 2097152){ src = u;   dst = u_bf;          o = g; }
    else if (g < 2105344){ src = Wom; dst = Wcat;          o = g - 2097152; }
    else if (g < 2113536){ src = Wze; dst = Wcat + 65536;  o = g - 2105344; }
    else if (g < 2129920){ src = WB;  dst = Wcat + 131072; o = g - 2113536; }
    else if (g < 2146304){ src = Cm;  dst = C_bf;          o = g - 2129920; }
    else                 { src = Dm;  dst = Dm_bf;         o = g - 2146304; }
    *(short8*)(dst + o*8) = ld8f(src + o*8);
  }
}

// ---------------------------------------------------------------------------
// K1 REWRITE: P[bt][n] = sum_d u[bt][d]*Wcat[n][d], (16384 x 256, K=1024).
// Tile 64x256 (BN = full N -> B staged ONCE per block, was re-staged 256x),
// BK=64, 512 threads = 8 waves (2 wm x 4 wn, wave tile 32x64), grid 256
// (1 block/CU). Same proven single-barrier 3-buffer pipeline, 16 K-steps.
// LDS layout per buffer: combined [320 rows][64 cols] bf16 (A rows 0..63,
// B rows 64..319), XOR-swizzled 16B slots: phys_slot = logical ^ (row&7).
// Staged linearly (5 x 8KB rounds, thread t -> row t>>3, slot t&7) with the
// inverse swizzle applied on the GLOBAL source address (rule #21).
// Accumulation k-order identical to the old BK=32 kernel -> bit-identical P.
// ---------------------------------------------------------------------------
extern "C" __global__ __launch_bounds__(512, 2) void k_gemm_p(
    const bf16raw* __restrict__ u_bf, const bf16raw* __restrict__ Wcat,
    float* __restrict__ P){
  __shared__ __align__(16) bf16raw Plds[3*320*64];   // 3 x 40 KB = 120 KB
  int tid = threadIdx.x, wave = tid >> 6, lane = tid & 63;
  int quad = lane >> 4, t16 = lane & 15;
  int wm = wave >> 2, wn = wave & 3;                 // 2x4 waves, tile 32x64
  long row0 = (long)blockIdx.x * 64;
  f32x4 acc[2][4] = {};

  auto stageP = [&](int kt, int buf){
    bf16raw* lb = Plds + buf*20480 + wave*512;       // wave-uniform dest base
    int row = tid >> 3, slot = tid & 7;
    int sl = ((slot ^ (row & 7)) * 8);               // inverse swizzle on source
    {
      const bf16raw* gp = u_bf + (row0 + row)*1024 + kt*64 + sl;
      __builtin_amdgcn_global_load_lds((const __attribute__((address_space(1))) void*)gp,
                                       (__attribute__((address_space(3))) void*)lb,
                                       16, 0, 0);
    }
#pragma unroll
    for (int r = 1; r < 5; ++r){
      long brow = (r-1)*64 + row;
      const bf16raw* gp = Wcat + brow*1024 + kt*64 + sl;
      __builtin_amdgcn_global_load_lds((const __attribute__((address_space(1))) void*)gp,
                                       (__attribute__((address_space(3))) void*)(lb + r*4096),
                                       16, 0, 0);
    }
  };

  auto mmaP = [&](int buf){
    const bf16raw* lb = Plds + buf*20480;
    short8 af[2][2], bfr[4][2];
    int swb = t16 & 7;
#pragma unroll
    for (int mi = 0; mi < 2; ++mi)
#pragma unroll
      for (int ks = 0; ks < 2; ++ks)
        af[mi][ks] = *(const short8*)(lb + (wm*32 + mi*16 + t16)*64 + ((ks*4 + quad) ^ swb)*8);
#pragma unroll
    for (int ni = 0; ni < 4; ++ni)
#pragma unroll
      for (int ks = 0; ks < 2; ++ks)
        bfr[ni][ks] = *(const short8*)(lb + (64 + wn*64 + ni*16 + t16)*64 + ((ks*4 + quad) ^ swb)*8);
#pragma unroll
    for (int ks = 0; ks < 2; ++ks)
#pragma unroll
      for (int mi = 0; mi < 2; ++mi)
#pragma unroll
        for (int ni = 0; ni < 4; ++ni)
          acc[mi][ni] = __builtin_amdgcn_mfma_f32_16x16x32_bf16(af[mi][ks], bfr[ni][ks], acc[mi][ni], 0, 0, 0);
  };

  stageP(0, 0);
  stageP(1, 1);
  int rd = 0;                                        // rd = s % 3
  for (int s = 0; s < 14; ++s){
    asm volatile("s_waitcnt vmcnt(5)" ::: "memory"); // own stage-s loads landed
    __builtin_amdgcn_s_barrier();                    // all waves' stage-s landed;
    __builtin_amdgcn_sched_barrier(0);               // buf (s-1)%3 fully consumed
    int st = rd >= 1 ? rd - 1 : 2;                   // (s+2)%3
    stageP(s + 2, st);                               // issue early, before MFMA
    __builtin_amdgcn_s_setprio(1);
    mmaP(rd);
    __builtin_amdgcn_s_setprio(0);
    rd = rd < 2 ? rd + 1 : 0;
  }
  asm volatile("s_waitcnt vmcnt(5)" ::: "memory");   // s=14 reads buf 2
  __builtin_amdgcn_s_barrier();
  __builtin_amdgcn_sched_barrier(0);
  mmaP(2);
  asm volatile("s_waitcnt vmcnt(0)" ::: "memory");   // s=15 reads buf 0
  __builtin_amdgcn_s_barrier();
  __builtin_amdgcn_sched_barrier(0);
  mmaP(0);
#pragma unroll
  for (int mi = 0; mi < 2; ++mi)
#pragma unroll
    for (int ni = 0; ni < 4; ++ni)
#pragma unroll
      for (int r = 0; r < 4; ++r){
        long grow = row0 + wm*32 + mi*16 + quad*4 + r;
        int  gcol = wn*64 + ni*16 + t16;
        P[grow*256 + gcol] = acc[mi][ni][r];
      }
}

// ---------------------------------------------------------------------------
// K4: out[bt][d] = sum_n Xs[bt][n]*C[d][n] + sum_e u[bt][e]*Dm[d][e], fp32 out.
// PROVEN round-4 config (52.2 us): tile 128x256, grid 512, 3-buffer
// single-barrier pipeline, vmcnt(6), LDS 72 KB -> 2 blocks/CU.
// ---------------------------------------------------------------------------
extern "C" __global__ __launch_bounds__(256, 2) void k_gemm_out(
    const bf16raw* __restrict__ Xs, const bf16raw* __restrict__ u_bf,
    const bf16raw* __restrict__ C_bf, const bf16raw* __restrict__ Dm_bf,
    float* __restrict__ out){
  __shared__ __align__(16) bf16raw Alds[3*128*32];   // 24 KB
  __shared__ __align__(16) bf16raw Blds[3*256*32];   // 48 KB
  int tid = threadIdx.x, wave = tid >> 6, lane = tid & 63;
  int quad = lane >> 4, t16 = lane & 15;
  int wm = wave >> 1, wn = wave & 1;                 // wave tile 64x128
  // XCD-aware swizzle: 512 blocks, 8 XCDs x 64 consecutive blocks each.
  int id  = blockIdx.y * gridDim.x + blockIdx.x;
  int sid = (id & 7) * 64 + (id >> 3);
  long row0 = (long)(sid >> 2) * 128;
  int  col0 = (sid & 3) * 256;
  f32x4 acc[4][8] = {};

  auto stage = [&](int s, int buf){
    if (s < 4){
      stage_async<2>(Xs,   128, row0, s*32, Alds + buf*(128*32), wave, lane);
      stage_async<4>(C_bf, 128, col0, s*32, Blds + buf*(256*32), wave, lane);
    } else {
      stage_async<2>(u_bf,  1024, row0, (s-4)*32, Alds + buf*(128*32), wave, lane);
      stage_async<4>(Dm_bf, 1024, col0, (s-4)*32, Blds + buf*(256*32), wave, lane);
    }
  };

  stage(0, 0);
  stage(1, 1);
  int rd = 0;                                        // rd = s % 3
  for (int s = 0; s < 34; ++s){
    asm volatile("s_waitcnt vmcnt(6)" ::: "memory");
    __builtin_amdgcn_s_barrier();
    __builtin_amdgcn_sched_barrier(0);
    int st = rd >= 1 ? rd - 1 : 2;                   // (s+2)%3
    stage(s + 2, st);
    __builtin_amdgcn_s_setprio(1);
    mma_tile<4,8>(Alds + rd*(128*32), Blds + rd*(256*32), acc, wm, wn, quad, t16);
    __builtin_amdgcn_s_setprio(0);
    rd = rd < 2 ? rd + 1 : 0;
  }
  asm volatile("s_waitcnt vmcnt(6)" ::: "memory");
  __builtin_amdgcn_s_barrier();
  __builtin_amdgcn_sched_barrier(0);
  mma_tile<4,8>(Alds + 1*(128*32), Blds + 1*(256*32), acc, wm, wn, quad, t16);
  asm volatile("s_waitcnt vmcnt(0)" ::: "memory");
  __builtin_amdgcn_s_barrier();
  __builtin_amdgcn_sched_barrier(0);
  mma_tile<4,8>(Alds + 2*(128*32), Blds + 2*(256*32), acc, wm, wn, quad, t16);
#pragma unroll
  for (int mi = 0; mi < 4; ++mi)
#pragma unroll
    for (int ni = 0; ni < 8; ++ni)
#pragma unroll
      for (int r = 0; r < 4; ++r){
        long grow = row0 + wm*64 + mi*16 + quad*4 + r;
        int  gcol = col0 + wn*128 + ni*16 + t16;
        out[grow*1024 + gcol] = acc[mi][ni][r];
      }
}

// ---------------------------------------------------------------------------
// scanA: coef + chunk summary. 256 chunks x 16 steps (r6-proven config).
// ---------------------------------------------------------------------------
extern "C" __global__ __launch_bounds__(256) void k_scanA(
    const float* __restrict__ P, const float* __restrict__ b_om,
    const float* __restrict__ b_ze, const float* __restrict__ b_B,
    float4* __restrict__ CM, float2* __restrict__ CV){
  int tid = threadIdx.x, c = blockIdx.x;
  int b = tid >> 6, m = tid & 63;
  float bo = b_om[m], bz = b_ze[m], bb0 = b_B[m], bb1 = b_B[64 + m];
  const float* row = P + ((size_t)b*4096 + c*16) * 256;
  float m00=1.f, m01=0.f, m10=0.f, m11=0.f, vz=0.f, vy=0.f;
#pragma unroll 4
  for (int t = 0; t < 16; ++t){
    const float* r = row + t*256;
    float wo = r[m]       + bo;
    float wz = r[64 + m]  + bz;
    float fz = r[128 + m] + bb0;
    float fy = r[192 + m] + bb1;
    float sp = (wo > 20.f) ? wo : log1pf(expf(wo));
    float omega = fminf(fmaxf(sp, 1e-4f), 100.f);
    float A = omega * omega;
    float S = 1.f / (1.f + DTC*DTC*A);
    float zeta = 1.f / (1.f + expf(-wz));
    float p = (1.f - zeta) * S;
    float q = p * DTC * A;
    float nvz = p*vz - q*vy + fz;
    float nvy = DTC*p*vz + p*vy + fy;
    vz = nvz; vy = nvy;
    float n00 = p*m00 - q*m10;
    float n01 = p*m01 - q*m11;
    float n10 = DTC*p*m00 + p*m10;
    float n11 = DTC*p*m01 + p*m11;
    m00=n00; m01=n01; m10=n10; m11=n11;
  }
  CM[c*256 + tid] = make_float4(m00, m01, m10, m11);
  CV[c*256 + tid] = make_float2(vz, vy);
}

// ---------------------------------------------------------------------------
// scanB: Kogge-Stone over 256 chunk summaries, block = series.
// XIn[c] = state entering chunk c (x0 = 0).
// ---------------------------------------------------------------------------
extern "C" __global__ __launch_bounds__(256) void k_scanB(
    const float4* __restrict__ CM, const float2* __restrict__ CV,
    float2* __restrict__ XIn){
  __shared__ float sm[6][256];
  int s = blockIdx.x;            // series (b*64+m)
  int c = threadIdx.x;           // chunk
  float4 Mv = CM[(size_t)c*256 + s];
  float2 Vv = CV[(size_t)c*256 + s];
  float m00=Mv.x, m01=Mv.y, m10=Mv.z, m11=Mv.w, vz=Vv.x, vy=Vv.y;
#pragma unroll
  for (int off = 1; off < 256; off <<= 1){
    sm[0][c]=m00; sm[1][c]=m01; sm[2][c]=m10; sm[3][c]=m11; sm[4][c]=vz; sm[5][c]=vy;
    __syncthreads();
    if (c >= off){
      int p = c - off;
      float e00=sm[0][p], e01=sm[1][p], e10=sm[2][p], e11=sm[3][p];
      float evz=sm[4][p], evy=sm[5][p];
      float n00 = m00*e00 + m01*e10;
      float n01 = m00*e01 + m01*e11;
      float n10 = m10*e00 + m11*e10;
      float n11 = m10*e01 + m11*e11;
      float nvz = m00*evz + m01*evy + vz;
      float nvy = m10*evz + m11*evy + vy;
      m00=n00; m01=n01; m10=n10; m11=n11; vz=nvz; vy=nvy;
    }
    __syncthreads();
  }
  if (c < 255) XIn[(size_t)(c+1)*256 + s] = make_float2(vz, vy);
  if (c == 0)  XIn[s] = make_float2(0.f, 0.f);
}

// ---------------------------------------------------------------------------
// scanC: streaming — chunk-start state from XIn, recompute coefs from P,
// apply 16-step chunk, write Xs (bf16).
// ---------------------------------------------------------------------------
extern "C" __global__ __launch_bounds__(256) void k_scanC(
    const float* __restrict__ P, const float* __restrict__ b_om,
    const float* __restrict__ b_ze, const float* __restrict__ b_B,
    const float2* __restrict__ XIn, bf16raw* __restrict__ Xs){
  int tid = threadIdx.x, c = blockIdx.x;
  int b = tid >> 6, m = tid & 63;
  float2 x0 = XIn[(size_t)c*256 + tid];
  float xz = x0.x, xy = x0.y;
  float bo = b_om[m], bz = b_ze[m], bb0 = b_B[m], bb1 = b_B[64 + m];
  const float* row = P + ((size_t)b*4096 + c*16) * 256;
  bf16raw* xp = Xs + ((size_t)b*4096 + c*16) * 128 + m;
#pragma unroll 4
  for (int t = 0; t < 16; ++t){
    const float* r = row + t*256;
    float wo = r[m]       + bo;
    float wz = r[64 + m]  + bz;
    float fz = r[128 + m] + bb0;
    float fy = r[192 + m] + bb1;
    float sp = (wo > 20.f) ? wo : log1pf(expf(wo));
    float omega = fminf(fmaxf(sp, 1e-4f), 100.f);
    float A = omega * omega;
    float S = 1.f / (1.f + DTC*DTC*A);
    float zeta = 1.f / (1.f + expf(-wz));
    float p = (1.f - zeta) * S;
    float q = p * DTC * A;
    float nz = p*xz - q*xy + fz;
    float ny = DTC*p*xz + p*xy + fy;
    xz = nz; xy = ny;
    xp[t*128]      = f2bf(xz);   // z part: n = m
    xp[t*128 + 64] = f2bf(xy);   // y part: n = 64 + m
  }
}

// ---------------------------------------------------------------------------
extern "C" void kernel_launch(void* const* d_in, const int* in_sizes, int n_in,
                              void* d_out, int out_size, void* d_ws, size_t ws_size,
                              hipStream_t stream){
  const float* u   = (const float*)d_in[0];
  const float* Wom = (const float*)d_in[1];
  const float* bom = (const float*)d_in[2];
  const float* Wze = (const float*)d_in[3];
  const float* bze = (const float*)d_in[4];
  const float* WB  = (const float*)d_in[5];
  const float* bB  = (const float*)d_in[6];
  const float* Cm  = (const float*)d_in[7];
  const float* Dm  = (const float*)d_in[8];
  float* out = (float*)d_out;

  char* ws = (char*)d_ws;
  size_t off = 0;
  bf16raw* u_bf  = (bf16raw*)(ws + off); off += (size_t)16777216*2;    // 32 MB
  bf16raw* Wcat  = (bf16raw*)(ws + off); off += (size_t)262144*2;      // 512 KB
  bf16raw* C_bf  = (bf16raw*)(ws + off); off += (size_t)131072*2;      // 256 KB
  bf16raw* Dm_bf = (bf16raw*)(ws + off); off += (size_t)1048576*2;     // 2 MB
  float*   P     = (float*)  (ws + off); off += (size_t)16384*256*4;   // 16 MB
  bf16raw* Xs    = (bf16raw*)(ws + off); off += (size_t)16384*128*2;   // 4 MB
  float4*  CMw   = (float4*) (ws + off); off += (size_t)256*256*16;    // 1 MB
  float2*  CVw   = (float2*) (ws + off); off += (size_t)256*256*8;     // 512 KB
  float2*  XIn   = (float2*) (ws + off); off += (size_t)256*256*8;     // 512 KB

  k_prep    <<<2048, 256, 0, stream>>>(u, Wom, Wze, WB, Cm, Dm, u_bf, Wcat, C_bf, Dm_bf);
  k_gemm_p  <<<256, 512, 0, stream>>>(u_bf, Wcat, P);
  k_scanA   <<<256, 256, 0, stream>>>(P, bom, bze, bB, CMw, CVw);
  k_scanB   <<<256, 256, 0, stream>>>(CMw, CVw, XIn);
  k_scanC   <<<256, 256, 0, stream>>>(P, bom, bze, bB, XIn, Xs);
  k_gemm_out<<<dim3(4, 128), 256, 0, stream>>>(Xs, u_bf, C_bf, Dm_bf, out);
}

// Round 12
// 209.647 us; speedup vs baseline: 1.7681x; 1.0183x over previous
//
#include <hip/hip_runtime.h>
#include <hip/hip_bf16.h>
#include <math.h>

#define DTC 0.01f

typedef __attribute__((ext_vector_type(8))) short short8;   // 8 x bf16 (4 VGPRs)
typedef __attribute__((ext_vector_type(4))) float f32x4;    // MFMA C/D
typedef unsigned short bf16raw;

__device__ __forceinline__ bf16raw f2bf(float f){
  union { unsigned u; float f; } v; v.f = f;
  unsigned r = v.u + 0x7FFF + ((v.u >> 16) & 1u);   // round-to-nearest-even
  return (bf16raw)(r >> 16);
}

// Load 8 consecutive fp32, round to 8 bf16.
__device__ __forceinline__ short8 ld8f(const float* __restrict__ p){
  float4 a = *(const float4*)p;
  float4 b = *(const float4*)(p + 4);
  short8 r;
  r[0] = (short)f2bf(a.x); r[1] = (short)f2bf(a.y);
  r[2] = (short)f2bf(a.z); r[3] = (short)f2bf(a.w);
  r[4] = (short)f2bf(b.x); r[5] = (short)f2bf(b.y);
  r[6] = (short)f2bf(b.z); r[7] = (short)f2bf(b.w);
  return r;
}

// ---------------------------------------------------------------------------
// Async-stage ITERS*16 rows x 32 bf16 -> LDS [row][32], T2-swizzled.
// LDS dest linear (global_load_lds HW requirement); 16B k-slot permuted on
// the GLOBAL side (rule #21). Reader applies the same involution.
// ---------------------------------------------------------------------------
template<int ITERS>
__device__ __forceinline__ void stage_async(const bf16raw* __restrict__ src, long ld,
                                            long row0, int k0, bf16raw* lds,
                                            int wave, int lane){
  int kchunk = (lane & 3) ^ ((lane >> 3) & 3);
#pragma unroll
  for (int i = 0; i < ITERS; ++i){
    int r0 = (wave*ITERS + i) * 16;
    long row = row0 + r0 + (lane >> 2);
    const bf16raw* gp = src + row*ld + k0 + kchunk*8;
    bf16raw* lp = lds + r0*32;
    __builtin_amdgcn_global_load_lds((const __attribute__((address_space(1))) void*)gp,
                                     (__attribute__((address_space(3))) void*)lp,
                                     16, 0, 0);
  }
}

// One gload (16 rows): iteration i of an ITERS-iter wave stage.
template<int ITERS>
__device__ __forceinline__ void stage_iter(const bf16raw* __restrict__ src, long ld,
                                           long row0, int k0, bf16raw* lds,
                                           int i, int wave, int lane){
  int kchunk = (lane & 3) ^ ((lane >> 3) & 3);
  int r0 = (wave*ITERS + i) * 16;
  long row = row0 + r0 + (lane >> 2);
  const bf16raw* gp = src + row*ld + k0 + kchunk*8;
  bf16raw* lp = lds + r0*32;
  __builtin_amdgcn_global_load_lds((const __attribute__((address_space(1))) void*)gp,
                                   (__attribute__((address_space(3))) void*)lp,
                                   16, 0, 0);
}

// One BK=32 step: MI A-frags + NI B-frags (ds_read_b128, swizzled slot) + MI*NI MFMA.
template<int MI, int NI>
__device__ __forceinline__ void mma_tile(const bf16raw* Alds, const bf16raw* Blds,
                                         f32x4 acc[MI][NI], int wm, int wn, int quad, int t16){
  short8 af[MI], bfr[NI];
  int sw = (quad ^ ((t16 >> 1) & 3)) * 8;   // physical 16B slot for this lane's rows
#pragma unroll
  for (int mi = 0; mi < MI; ++mi)
    af[mi] = *(const short8*)(Alds + (wm*(MI*16) + mi*16 + t16)*32 + sw);
#pragma unroll
  for (int ni = 0; ni < NI; ++ni)
    bfr[ni] = *(const short8*)(Blds + (wn*(NI*16) + ni*16 + t16)*32 + sw);
#pragma unroll
  for (int mi = 0; mi < MI; ++mi)
#pragma unroll
    for (int ni = 0; ni < NI; ++ni)
      acc[mi][ni] = __builtin_amdgcn_mfma_f32_16x16x32_bf16(af[mi], bfr[ni], acc[mi][ni], 0, 0, 0);
}

// ---------------------------------------------------------------------------
// Prep: fp32 -> bf16 for u, [W_omega|W_zeta|W_B] (concat), C, D_mat.
// Grid-stride, 2048 blocks.
// ---------------------------------------------------------------------------
extern "C" __global__ void k_prep(const float* __restrict__ u,
    const float* __restrict__ Wom, const float* __restrict__ Wze,
    const float* __restrict__ WB, const float* __restrict__ Cm,
    const float* __restrict__ Dm, bf16raw* __restrict__ u_bf,
    bf16raw* __restrict__ Wcat, bf16raw* __restrict__ C_bf,
    bf16raw* __restrict__ Dm_bf){
  for (long g = (long)blockIdx.x * 256 + threadIdx.x; g < 2277376;
       g += (long)gridDim.x * 256){
    const float* src; bf16raw* dst; long o;
    if      (g < 2097152){ src = u;   dst = u_bf;          o = g; }
    else if (g < 2105344){ src = Wom; dst = Wcat;          o = g - 2097152; }
    else if (g < 2113536){ src = Wze; dst = Wcat + 65536;  o = g - 2105344; }
    else if (g < 2129920){ src = WB;  dst = Wcat + 131072; o = g - 2113536; }
    else if (g < 2146304){ src = Cm;  dst = C_bf;          o = g - 2129920; }
    else                 { src = Dm;  dst = Dm_bf;         o = g - 2146304; }
    *(short8*)(dst + o*8) = ld8f(src + o*8);
  }
}

// ---------------------------------------------------------------------------
// K1: P[bt][n] = sum_d u[bt][d]*Wcat[n][d], (16384 x 256, K=1024).
// r10 config (passed): tile 64x256, BK=64, 512 thr/8 waves, grid 256,
// single-barrier 3-buffer pipeline, combined XOR-swizzled LDS.
// ---------------------------------------------------------------------------
extern "C" __global__ __launch_bounds__(512, 2) void k_gemm_p(
    const bf16raw* __restrict__ u_bf, const bf16raw* __restrict__ Wcat,
    float* __restrict__ P){
  __shared__ __align__(16) bf16raw Plds[3*320*64];   // 3 x 40 KB = 120 KB
  int tid = threadIdx.x, wave = tid >> 6, lane = tid & 63;
  int quad = lane >> 4, t16 = lane & 15;
  int wm = wave >> 2, wn = wave & 3;                 // 2x4 waves, tile 32x64
  long row0 = (long)blockIdx.x * 64;
  f32x4 acc[2][4] = {};

  auto stageP = [&](int kt, int buf){
    bf16raw* lb = Plds + buf*20480 + wave*512;       // wave-uniform dest base
    int row = tid >> 3, slot = tid & 7;
    int sl = ((slot ^ (row & 7)) * 8);               // inverse swizzle on source
    {
      const bf16raw* gp = u_bf + (row0 + row)*1024 + kt*64 + sl;
      __builtin_amdgcn_global_load_lds((const __attribute__((address_space(1))) void*)gp,
                                       (__attribute__((address_space(3))) void*)lb,
                                       16, 0, 0);
    }
#pragma unroll
    for (int r = 1; r < 5; ++r){
      long brow = (r-1)*64 + row;
      const bf16raw* gp = Wcat + brow*1024 + kt*64 + sl;
      __builtin_amdgcn_global_load_lds((const __attribute__((address_space(1))) void*)gp,
                                       (__attribute__((address_space(3))) void*)(lb + r*4096),
                                       16, 0, 0);
    }
  };

  auto mmaP = [&](int buf){
    const bf16raw* lb = Plds + buf*20480;
    short8 af[2][2], bfr[4][2];
    int swb = t16 & 7;
#pragma unroll
    for (int mi = 0; mi < 2; ++mi)
#pragma unroll
      for (int ks = 0; ks < 2; ++ks)
        af[mi][ks] = *(const short8*)(lb + (wm*32 + mi*16 + t16)*64 + ((ks*4 + quad) ^ swb)*8);
#pragma unroll
    for (int ni = 0; ni < 4; ++ni)
#pragma unroll
      for (int ks = 0; ks < 2; ++ks)
        bfr[ni][ks] = *(const short8*)(lb + (64 + wn*64 + ni*16 + t16)*64 + ((ks*4 + quad) ^ swb)*8);
#pragma unroll
    for (int ks = 0; ks < 2; ++ks)
#pragma unroll
      for (int mi = 0; mi < 2; ++mi)
#pragma unroll
        for (int ni = 0; ni < 4; ++ni)
          acc[mi][ni] = __builtin_amdgcn_mfma_f32_16x16x32_bf16(af[mi][ks], bfr[ni][ks], acc[mi][ni], 0, 0, 0);
  };

  stageP(0, 0);
  stageP(1, 1);
  int rd = 0;                                        // rd = s % 3
  for (int s = 0; s < 14; ++s){
    asm volatile("s_waitcnt vmcnt(5)" ::: "memory");
    __builtin_amdgcn_s_barrier();
    __builtin_amdgcn_sched_barrier(0);
    int st = rd >= 1 ? rd - 1 : 2;                   // (s+2)%3
    stageP(s + 2, st);
    __builtin_amdgcn_s_setprio(1);
    mmaP(rd);
    __builtin_amdgcn_s_setprio(0);
    rd = rd < 2 ? rd + 1 : 0;
  }
  asm volatile("s_waitcnt vmcnt(5)" ::: "memory");
  __builtin_amdgcn_s_barrier();
  __builtin_amdgcn_sched_barrier(0);
  mmaP(2);
  asm volatile("s_waitcnt vmcnt(0)" ::: "memory");
  __builtin_amdgcn_s_barrier();
  __builtin_amdgcn_sched_barrier(0);
  mmaP(0);
#pragma unroll
  for (int mi = 0; mi < 2; ++mi)
#pragma unroll
    for (int ni = 0; ni < 4; ++ni)
#pragma unroll
      for (int r = 0; r < 4; ++r){
        long grow = row0 + wm*32 + mi*16 + quad*4 + r;
        int  gcol = wn*64 + ni*16 + t16;
        P[grow*256 + gcol] = acc[mi][ni][r];
      }
}

// ---------------------------------------------------------------------------
// K4: out[bt][d] = sum_n Xs[bt][n]*C[d][n] + sum_e u[bt][e]*Dm[d][e].
// PROVEN r4 skeleton (tile 128x256, 256 thr, grid 512, 3-buffer, vmcnt(6),
// one head barrier/step) + PHASE-SPLIT-LITE: each step's compute is split
// into 2 phases {ds_read half | issue half of stage(s+2) | lgkmcnt(0) |
// setprio(1) 16 MFMA setprio(0)}. Buffer lifetimes, barrier count, stage
// targets and per-accumulator K-order identical to the passing kernel ->
// bit-identical output.
// ---------------------------------------------------------------------------
extern "C" __global__ __launch_bounds__(256, 2) void k_gemm_out(
    const bf16raw* __restrict__ Xs, const bf16raw* __restrict__ u_bf,
    const bf16raw* __restrict__ C_bf, const bf16raw* __restrict__ Dm_bf,
    float* __restrict__ out){
  __shared__ __align__(16) bf16raw Alds[3*128*32];   // 24 KB
  __shared__ __align__(16) bf16raw Blds[3*256*32];   // 48 KB
  int tid = threadIdx.x, wave = tid >> 6, lane = tid & 63;
  int quad = lane >> 4, t16 = lane & 15;
  int wm = wave >> 1, wn = wave & 1;                 // wave tile 64x128
  // XCD-aware swizzle: 512 blocks, 8 XCDs x 64 consecutive blocks each.
  int id  = blockIdx.y * gridDim.x + blockIdx.x;
  int sid = (id & 7) * 64 + (id >> 3);
  long row0 = (long)(sid >> 2) * 128;
  int  col0 = (sid & 3) * 256;
  f32x4 acc[4][8] = {};
  int sw = (quad ^ ((t16 >> 1) & 3)) * 8;

  auto stage = [&](int s, int buf){                  // full stage (prologue)
    if (s < 4){
      stage_async<2>(Xs,   128, row0, s*32, Alds + buf*4096, wave, lane);
      stage_async<4>(C_bf, 128, col0, s*32, Blds + buf*8192, wave, lane);
    } else {
      stage_async<2>(u_bf,  1024, row0, (s-4)*32, Alds + buf*4096, wave, lane);
      stage_async<4>(Dm_bf, 1024, col0, (s-4)*32, Blds + buf*8192, wave, lane);
    }
  };
  // Half-stages: h0 = A(2 gloads) + B iters 0,1 ; h1 = B iters 2,3.
  auto stage_h0 = [&](int s, int buf){
    if (s < 4){
      stage_async<2>(Xs, 128, row0, s*32, Alds + buf*4096, wave, lane);
      stage_iter<4>(C_bf, 128, col0, s*32, Blds + buf*8192, 0, wave, lane);
      stage_iter<4>(C_bf, 128, col0, s*32, Blds + buf*8192, 1, wave, lane);
    } else {
      stage_async<2>(u_bf, 1024, row0, (s-4)*32, Alds + buf*4096, wave, lane);
      stage_iter<4>(Dm_bf, 1024, col0, (s-4)*32, Blds + buf*8192, 0, wave, lane);
      stage_iter<4>(Dm_bf, 1024, col0, (s-4)*32, Blds + buf*8192, 1, wave, lane);
    }
  };
  auto stage_h1 = [&](int s, int buf){
    if (s < 4){
      stage_iter<4>(C_bf, 128, col0, s*32, Blds + buf*8192, 2, wave, lane);
      stage_iter<4>(C_bf, 128, col0, s*32, Blds + buf*8192, 3, wave, lane);
    } else {
      stage_iter<4>(Dm_bf, 1024, col0, (s-4)*32, Blds + buf*8192, 2, wave, lane);
      stage_iter<4>(Dm_bf, 1024, col0, (s-4)*32, Blds + buf*8192, 3, wave, lane);
    }
  };

  stage(0, 0);
  stage(1, 1);
  int rd = 0;                                        // rd = s % 3
  for (int s = 0; s < 34; ++s){
    asm volatile("s_waitcnt vmcnt(6)" ::: "memory"); // stage s landed
    __builtin_amdgcn_s_barrier();                    // buf (s-1)%3 free
    __builtin_amdgcn_sched_barrier(0);
    int st = rd >= 1 ? rd - 1 : 2;                   // (s+2)%3
    const bf16raw* A = Alds + rd*4096;
    const bf16raw* B = Blds + rd*8192;
    short8 af[4], bfr[4];
    // ---- phase 0: A-frags + B-frags 0..3, issue half-stage, 16 MFMA ----
#pragma unroll
    for (int mi = 0; mi < 4; ++mi)
      af[mi] = *(const short8*)(A + (wm*64 + mi*16 + t16)*32 + sw);
#pragma unroll
    for (int ni = 0; ni < 4; ++ni)
      bfr[ni] = *(const short8*)(B + (wn*128 + ni*16 + t16)*32 + sw);
    stage_h0(s + 2, st);
    asm volatile("s_waitcnt lgkmcnt(0)" ::: "memory");
    __builtin_amdgcn_sched_barrier(0);
    __builtin_amdgcn_s_setprio(1);
#pragma unroll
    for (int mi = 0; mi < 4; ++mi)
#pragma unroll
      for (int ni = 0; ni < 4; ++ni)
        acc[mi][ni] = __builtin_amdgcn_mfma_f32_16x16x32_bf16(af[mi], bfr[ni], acc[mi][ni], 0, 0, 0);
    __builtin_amdgcn_s_setprio(0);
    __builtin_amdgcn_sched_barrier(0);
    // ---- phase 1: B-frags 4..7, issue rest of stage, 16 MFMA ----
#pragma unroll
    for (int ni = 0; ni < 4; ++ni)
      bfr[ni] = *(const short8*)(B + (wn*128 + (4+ni)*16 + t16)*32 + sw);
    stage_h1(s + 2, st);
    asm volatile("s_waitcnt lgkmcnt(0)" ::: "memory");
    __builtin_amdgcn_sched_barrier(0);
    __builtin_amdgcn_s_setprio(1);
#pragma unroll
    for (int mi = 0; mi < 4; ++mi)
#pragma unroll
      for (int ni = 0; ni < 4; ++ni)
        acc[mi][4+ni] = __builtin_amdgcn_mfma_f32_16x16x32_bf16(af[mi], bfr[ni], acc[mi][4+ni], 0, 0, 0);
    __builtin_amdgcn_s_setprio(0);
    __builtin_amdgcn_sched_barrier(0);
    rd = rd < 2 ? rd + 1 : 0;
  }
  asm volatile("s_waitcnt vmcnt(6)" ::: "memory");   // s=34 reads buf 1
  __builtin_amdgcn_s_barrier();
  __builtin_amdgcn_sched_barrier(0);
  mma_tile<4,8>(Alds + 1*4096, Blds + 1*8192, acc, wm, wn, quad, t16);
  asm volatile("s_waitcnt vmcnt(0)" ::: "memory");   // s=35 reads buf 2
  __builtin_amdgcn_s_barrier();
  __builtin_amdgcn_sched_barrier(0);
  mma_tile<4,8>(Alds + 2*4096, Blds + 2*8192, acc, wm, wn, quad, t16);
#pragma unroll
  for (int mi = 0; mi < 4; ++mi)
#pragma unroll
    for (int ni = 0; ni < 8; ++ni)
#pragma unroll
      for (int r = 0; r < 4; ++r){
        long grow = row0 + wm*64 + mi*16 + quad*4 + r;
        int  gcol = col0 + wn*128 + ni*16 + t16;
        out[grow*1024 + gcol] = acc[mi][ni][r];
      }
}

// ---------------------------------------------------------------------------
// scanA: coef + chunk summary. 256 chunks x 16 steps (r6-proven config).
// ---------------------------------------------------------------------------
extern "C" __global__ __launch_bounds__(256) void k_scanA(
    const float* __restrict__ P, const float* __restrict__ b_om,
    const float* __restrict__ b_ze, const float* __restrict__ b_B,
    float4* __restrict__ CM, float2* __restrict__ CV){
  int tid = threadIdx.x, c = blockIdx.x;
  int b = tid >> 6, m = tid & 63;
  float bo = b_om[m], bz = b_ze[m], bb0 = b_B[m], bb1 = b_B[64 + m];
  const float* row = P + ((size_t)b*4096 + c*16) * 256;
  float m00=1.f, m01=0.f, m10=0.f, m11=0.f, vz=0.f, vy=0.f;
#pragma unroll 4
  for (int t = 0; t < 16; ++t){
    const float* r = row + t*256;
    float wo = r[m]       + bo;
    float wz = r[64 + m]  + bz;
    float fz = r[128 + m] + bb0;
    float fy = r[192 + m] + bb1;
    float sp = (wo > 20.f) ? wo : log1pf(expf(wo));
    float omega = fminf(fmaxf(sp, 1e-4f), 100.f);
    float A = omega * omega;
    float S = 1.f / (1.f + DTC*DTC*A);
    float zeta = 1.f / (1.f + expf(-wz));
    float p = (1.f - zeta) * S;
    float q = p * DTC * A;
    float nvz = p*vz - q*vy + fz;
    float nvy = DTC*p*vz + p*vy + fy;
    vz = nvz; vy = nvy;
    float n00 = p*m00 - q*m10;
    float n01 = p*m01 - q*m11;
    float n10 = DTC*p*m00 + p*m10;
    float n11 = DTC*p*m01 + p*m11;
    m00=n00; m01=n01; m10=n10; m11=n11;
  }
  CM[c*256 + tid] = make_float4(m00, m01, m10, m11);
  CV[c*256 + tid] = make_float2(vz, vy);
}

// ---------------------------------------------------------------------------
// scanB: Kogge-Stone over 256 chunk summaries, block = series.
// XIn[c] = state entering chunk c (x0 = 0).
// ---------------------------------------------------------------------------
extern "C" __global__ __launch_bounds__(256) void k_scanB(
    const float4* __restrict__ CM, const float2* __restrict__ CV,
    float2* __restrict__ XIn){
  __shared__ float sm[6][256];
  int s = blockIdx.x;            // series (b*64+m)
  int c = threadIdx.x;           // chunk
  float4 Mv = CM[(size_t)c*256 + s];
  float2 Vv = CV[(size_t)c*256 + s];
  float m00=Mv.x, m01=Mv.y, m10=Mv.z, m11=Mv.w, vz=Vv.x, vy=Vv.y;
#pragma unroll
  for (int off = 1; off < 256; off <<= 1){
    sm[0][c]=m00; sm[1][c]=m01; sm[2][c]=m10; sm[3][c]=m11; sm[4][c]=vz; sm[5][c]=vy;
    __syncthreads();
    if (c >= off){
      int p = c - off;
      float e00=sm[0][p], e01=sm[1][p], e10=sm[2][p], e11=sm[3][p];
      float evz=sm[4][p], evy=sm[5][p];
      float n00 = m00*e00 + m01*e10;
      float n01 = m00*e01 + m01*e11;
      float n10 = m10*e00 + m11*e10;
      float n11 = m10*e01 + m11*e11;
      float nvz = m00*evz + m01*evy + vz;
      float nvy = m10*evz + m11*evy + vy;
      m00=n00; m01=n01; m10=n10; m11=n11; vz=nvz; vy=nvy;
    }
    __syncthreads();
  }
  if (c < 255) XIn[(size_t)(c+1)*256 + s] = make_float2(vz, vy);
  if (c == 0)  XIn[s] = make_float2(0.f, 0.f);
}

// ---------------------------------------------------------------------------
// scanC: streaming — chunk-start state from XIn, recompute coefs from P,
// apply 16-step chunk, write Xs (bf16).
// ---------------------------------------------------------------------------
extern "C" __global__ __launch_bounds__(256) void k_scanC(
    const float* __restrict__ P, const float* __restrict__ b_om,
    const float* __restrict__ b_ze, const float* __restrict__ b_B,
    const float2* __restrict__ XIn, bf16raw* __restrict__ Xs){
  int tid = threadIdx.x, c = blockIdx.x;
  int b = tid >> 6, m = tid & 63;
  float2 x0 = XIn[(size_t)c*256 + tid];
  float xz = x0.x, xy = x0.y;
  float bo = b_om[m], bz = b_ze[m], bb0 = b_B[m], bb1 = b_B[64 + m];
  const float* row = P + ((size_t)b*4096 + c*16) * 256;
  bf16raw* xp = Xs + ((size_t)b*4096 + c*16) * 128 + m;
#pragma unroll 4
  for (int t = 0; t < 16; ++t){
    const float* r = row + t*256;
    float wo = r[m]       + bo;
    float wz = r[64 + m]  + bz;
    float fz = r[128 + m] + bb0;
    float fy = r[192 + m] + bb1;
    float sp = (wo > 20.f) ? wo : log1pf(expf(wo));
    float omega = fminf(fmaxf(sp, 1e-4f), 100.f);
    float A = omega * omega;
    float S = 1.f / (1.f + DTC*DTC*A);
    float zeta = 1.f / (1.f + expf(-wz));
    float p = (1.f - zeta) * S;
    float q = p * DTC * A;
    float nz = p*xz - q*xy + fz;
    float ny = DTC*p*xz + p*xy + fy;
    xz = nz; xy = ny;
    xp[t*128]      = f2bf(xz);   // z part: n = m
    xp[t*128 + 64] = f2bf(xy);   // y part: n = 64 + m
  }
}

// ---------------------------------------------------------------------------
extern "C" void kernel_launch(void* const* d_in, const int* in_sizes, int n_in,
                              void* d_out, int out_size, void* d_ws, size_t ws_size,
                              hipStream_t stream){
  const float* u   = (const float*)d_in[0];
  const float* Wom = (const float*)d_in[1];
  const float* bom = (const float*)d_in[2];
  const float* Wze = (const float*)d_in[3];
  const float* bze = (const float*)d_in[4];
  const float* WB  = (const float*)d_in[5];
  const float* bB  = (const float*)d_in[6];
  const float* Cm  = (const float*)d_in[7];
  const float* Dm  = (const float*)d_in[8];
  float* out = (float*)d_out;

  char* ws = (char*)d_ws;
  size_t off = 0;
  bf16raw* u_bf  = (bf16raw*)(ws + off); off += (size_t)16777216*2;    // 32 MB
  bf16raw* Wcat  = (bf16raw*)(ws + off); off += (size_t)262144*2;      // 512 KB
  bf16raw* C_bf  = (bf16raw*)(ws + off); off += (size_t)131072*2;      // 256 KB
  bf16raw* Dm_bf = (bf16raw*)(ws + off); off += (size_t)1048576*2;     // 2 MB
  float*   P     = (float*)  (ws + off); off += (size_t)16384*256*4;   // 16 MB
  bf16raw* Xs    = (bf16raw*)(ws + off); off += (size_t)16384*128*2;   // 4 MB
  float4*  CMw   = (float4*) (ws + off); off += (size_t)256*256*16;    // 1 MB
  float2*  CVw   = (float2*) (ws + off); off += (size_t)256*256*8;     // 512 KB
  float2*  XIn   = (float2*) (ws + off); off += (size_t)256*256*8;     // 512 KB

  k_prep    <<<2048, 256, 0, stream>>>(u, Wom, Wze, WB, Cm, Dm, u_bf, Wcat, C_bf, Dm_bf);
  k_gemm_p  <<<256, 512, 0, stream>>>(u_bf, Wcat, P);
  k_scanA   <<<256, 256, 0, stream>>>(P, bom, bze, bB, CMw, CVw);
  k_scanB   <<<256, 256, 0, stream>>>(CMw, CVw, XIn);
  k_scanC   <<<256, 256, 0, stream>>>(P, bom, bze, bB, XIn, Xs);
  k_gemm_out<<<dim3(4, 128), 256, 0, stream>>>(Xs, u_bf, C_bf, Dm_bf, out);
}